// Round 14
// baseline (4229.181 us; speedup 1.0000x reference)
//
#include <hip/hip_runtime.h>
#include <hip/hip_bf16.h>

typedef unsigned short u16;
typedef unsigned int u32;
typedef unsigned long long u64;
typedef __attribute__((ext_vector_type(8))) short short8;
typedef __attribute__((ext_vector_type(4))) float f32x4;
typedef __attribute__((ext_vector_type(4))) u32 u32x4;

#define ROWS 25600  // B*T = 32*800
#define POISON 0x7FC07FC0u  // bf16 NaN pair — never produced by sig*tanh

__device__ __forceinline__ u16 f2bf(float f){
  u32 x = __builtin_bit_cast(u32, f);
  u32 r = (x + 0x7FFFu + ((x >> 16) & 1u)) >> 16;
  return (u16)r;
}
__device__ __forceinline__ float bf2f(u16 h){
  return __builtin_bit_cast(float, ((u32)h) << 16);
}
__device__ __forceinline__ float sigf(float x){
  x = fminf(fmaxf(x, -30.f), 30.f);
  return 1.f / (1.f + __expf(-x));
}
__device__ __forceinline__ float tanh_(float x){
  x = fminf(fmaxf(x, -15.f), 15.f);
  float e = __expf(-2.f * x);
  return (1.f - e) / (1.f + e);
}

// ---------------------------------------------------------------- init / prep

__global__ void initk(u32* wflags, u32* pflags, u32* hstep){
  int i = blockIdx.x * blockDim.x + threadIdx.x;
  int stride = blockDim.x * gridDim.x;
  for (int j = i; j < 64 * 32; j += stride) wflags[j] = 0;
  for (int j = i; j < 192 * 32; j += stride) pflags[j] = 0;
  // hstep: 801 slots x 16384 u32. Slot 0 = zeros (h_0), rest = poison.
  const int total = 801 * 16384;
  for (int j = i; j < total; j += stride)
    hstep[j] = (j < 16384) ? 0u : POISON;
}

__global__ void sentinel_fill(float* out, int n, float val){
  for (int i = blockIdx.x * blockDim.x + threadIdx.x; i < n;
       i += blockDim.x * gridDim.x)
    out[i] = val;
}

__global__ void prep_prev(const float* __restrict__ ym, u16* __restrict__ prevp){
  int idx = blockIdx.x * blockDim.x + threadIdx.x;
  if (idx >= ROWS * 96) return;
  int r = idx / 96, c = idx - r * 96;
  int b = r / 800, t = r - b * 800;
  float v = 0.f;
  if (c < 80 && t > 0) v = ym[(u64)(b * 800 + (t - 1)) * 80 + c];
  prevp[idx] = f2bf(v);
}

__global__ void prep_w(const float* __restrict__ w1, const float* __restrict__ w2,
                       const float* __restrict__ wih, const float* __restrict__ pw,
                       const float* __restrict__ bih, const float* __restrict__ bhh,
                       const float* __restrict__ whh,
                       u16* __restrict__ w1p, u16* __restrict__ w2b,
                       u16* __restrict__ wihb, u16* __restrict__ projp,
                       float* __restrict__ bsum, u16* __restrict__ whhb){
  int idx = blockIdx.x * blockDim.x + threadIdx.x;
  const int n1 = 256 * 96, n2 = 256 * 256, n3 = 4096 * 768, n4 = 128 * 1536, n5 = 4096;
  const int n6 = 4096 * 1024;
  if (idx < n1){
    int r = idx / 96, c = idx - r * 96;
    w1p[idx] = (c < 80) ? f2bf(w1[r * 80 + c]) : (u16)0;
  } else if ((idx -= n1) < n2){
    w2b[idx] = f2bf(w2[idx]);
  } else if ((idx -= n2) < n3){
    wihb[idx] = f2bf(wih[idx]);
  } else if ((idx -= n3) < n4){
    int r = idx / 1536;
    projp[idx] = (r < 80) ? f2bf(pw[idx]) : (u16)0;
  } else if ((idx -= n4) < n5){
    bsum[idx] = bih[idx] + bhh[idx];
  } else if ((idx -= n5) < n6){
    whhb[idx] = f2bf(whh[idx]);
  }
}

// ------------------------------------------------------------ generic TN GEMM
// C[orow(m),n] = act( sum_k A[arow,k]*W[n,k] + bias[n] ).  W:[N,K] bf16.
// AMAP/A2MAP/OMAP: apply t-major<->b-major row map (gr&31)*800 + t0 + (gr>>5)
// to A / A2 / C row indices. SPLIT: k>=ksplit from A2 (f32).

template<int RELU, int OUTF32, int HASBIAS, int AMAP, int A2MAP, int OMAP, int SPLIT>
__global__ __launch_bounds__(256, 2) void gemm_tn(
    const u16* __restrict__ A, const float* __restrict__ A2,
    const u16* __restrict__ W, void* __restrict__ Cv,
    const float* __restrict__ bias,
    int M, int K, int lda, int lda2, int ldw, int ldc, int nmax,
    int ksplit, int t0)
{
  __shared__ __align__(16) u16 As[128 * 32];
  __shared__ __align__(16) u16 Ws[128 * 32];
  const int tid = threadIdx.x;
  const int lane = tid & 63;
  const int wv = tid >> 6;
  const int wr = wv & 1, wc = wv >> 1;
  const int mtiles = M >> 7;
  const int ntiles = gridDim.x / mtiles;
  int bm, bn;
  if (mtiles & 7){
    bm = blockIdx.x % mtiles;
    bn = blockIdx.x / mtiles;
  } else {
    int per = 8 * ntiles;
    int g = blockIdx.x / per, rem = blockIdx.x % per;
    bm = g * 8 + (rem & 7);
    bn = rem >> 3;
  }
  const int m0 = bm << 7, n0 = bn << 7;
  const int KT = K >> 5;

  f32x4 acc[4][4] = {};

  const int r0 = tid >> 2, c0 = tid & 3;
  const int r1 = r0 + 64;
  const u16* Wb = W + (u64)n0 * ldw;
  const int ws0 = r0 * 32 + ((c0 ^ ((r0 >> 1) & 3)) << 3);
  const int ws1 = r1 * 32 + ((c0 ^ ((r1 >> 1) & 3)) << 3);

  auto maprow = [&](int r) -> int {
    int gr = m0 + r;
    return (gr & 31) * 800 + t0 + (gr >> 5);
  };
  const u64 ab0 = (u64)(AMAP  ? maprow(r0) : m0 + r0) * lda;
  const u64 ab1 = (u64)(AMAP  ? maprow(r1) : m0 + r1) * lda;
  const u64 af0 = SPLIT ? (u64)(A2MAP ? maprow(r0) : m0 + r0) * lda2 : 0;
  const u64 af1 = SPLIT ? (u64)(A2MAP ? maprow(r1) : m0 + r1) * lda2 : 0;

  auto aload = [&](u64 rb, u64 rf, int k) -> uint4 {
    if (SPLIT && k >= ksplit){
      const float* p = A2 + rf + (k - ksplit);
      const float4 a = *(const float4*)p;
      const float4 b = *(const float4*)(p + 4);
      uint4 r;
      r.x = (u32)f2bf(a.x) | ((u32)f2bf(a.y) << 16);
      r.y = (u32)f2bf(a.z) | ((u32)f2bf(a.w) << 16);
      r.z = (u32)f2bf(b.x) | ((u32)f2bf(b.y) << 16);
      r.w = (u32)f2bf(b.z) | ((u32)f2bf(b.w) << 16);
      return r;
    }
    return *(const uint4*)(A + rb + k);
  };

  uint4 ra0 = aload(ab0, af0, c0 * 8);
  uint4 ra1 = aload(ab1, af1, c0 * 8);
  uint4 rw0 = *(const uint4*)(Wb + r0 * ldw + c0 * 8);
  uint4 rw1 = *(const uint4*)(Wb + r1 * ldw + c0 * 8);

  const int r16 = lane & 15, cg = lane >> 4;

  for (int kt = 0; kt < KT; ++kt){
    *(uint4*)&As[ws0] = ra0;
    *(uint4*)&As[ws1] = ra1;
    *(uint4*)&Ws[ws0] = rw0;
    *(uint4*)&Ws[ws1] = rw1;
    __syncthreads();
    if (kt + 1 < KT){
      const int k0 = ((kt + 1) << 5) + c0 * 8;
      ra0 = aload(ab0, af0, k0);
      ra1 = aload(ab1, af1, k0);
      rw0 = *(const uint4*)(Wb + r0 * ldw + k0);
      rw1 = *(const uint4*)(Wb + r1 * ldw + k0);
    }
    short8 af[4], wf[4];
    #pragma unroll
    for (int mt = 0; mt < 4; ++mt){
      const int row = (wr << 6) + (mt << 4) + r16;
      af[mt] = *(const short8*)&As[(row << 5) + ((cg ^ ((row >> 1) & 3)) << 3)];
    }
    #pragma unroll
    for (int nt = 0; nt < 4; ++nt){
      const int row = (wc << 6) + (nt << 4) + r16;
      wf[nt] = *(const short8*)&Ws[(row << 5) + ((cg ^ ((row >> 1) & 3)) << 3)];
    }
    #pragma unroll
    for (int mt = 0; mt < 4; ++mt)
      #pragma unroll
      for (int nt = 0; nt < 4; ++nt)
        acc[mt][nt] = __builtin_amdgcn_mfma_f32_16x16x32_bf16(af[mt], wf[nt], acc[mt][nt], 0, 0, 0);
    __syncthreads();
  }

  #pragma unroll
  for (int nt = 0; nt < 4; ++nt){
    const int gn = n0 + (wc << 6) + (nt << 4) + r16;
    if (gn < nmax){
      float bv = 0.f;
      if (HASBIAS) bv = bias[gn];
      #pragma unroll
      for (int mt = 0; mt < 4; ++mt){
        #pragma unroll
        for (int r = 0; r < 4; ++r){
          const int gm = m0 + (wr << 6) + (mt << 4) + (cg << 2) + r;
          float v = acc[mt][nt][r] + bv;
          if (RELU) v = fmaxf(v, 0.f);
          const int orow = OMAP ? ((gm & 31) * 800 + t0 + (gm >> 5)) : gm;
          if (OUTF32) ((float*)Cv)[(u64)orow * ldc + gn] = v;
          else        ((u16*)Cv)[(u64)orow * ldc + gn] = f2bf(v);
        }
      }
    }
  }
}

// ==================== fused persistent producer/consumer kernel ==============
// grid = 256 x 512 threads, 1 WG/CU (88KB LDS).
//   blockIdx 0..63   : LSTM workers.
//   blockIdx 64..255 : producers — gates GEMM chunk-by-chunk into 2-slot ring.
// r14 protocol — DATA-IS-THE-FLAG: h for step t lives in a per-step slot
// hstep[t] (written exactly once, poison-initialized). Publish = packed-u32
// relaxed AGENT atomics (MALL). Read = coalesced sc0+sc1 dwordx4 with
// per-thread poison-retry — no flags, no fences, no drain, 2 barriers/step.
// hstep doubles as the h history consumed by the projection GEMM (OMAP).
// wflags are chunk-granular (pace producers' ring-slot reuse only).

__shared__ __align__(16) u16 fs_hsm[32 * 1024];  // 64KB worker h tile
__shared__ __align__(16) float fs_gsm[2048];     // 8KB worker gate exchange
__shared__ __align__(16) u16 fs_As[128 * 32];    // 8KB producer A tile
__shared__ __align__(16) u16 fs_Ws[128 * 32];    // 8KB producer W tile

__device__ void gemm_tile_512(
    const u16* __restrict__ pn, const float* __restrict__ memory,
    const u16* __restrict__ wihb, const float* __restrict__ bsum,
    u16* __restrict__ slot, int bm, int bn, int t0)
{
  const int tid = threadIdx.x;
  const bool act = (tid < 256);
  const int lane = tid & 63;
  const int wv4 = (tid >> 6) & 3;
  const int wr = wv4 & 1, wc = wv4 >> 1;
  const int m0 = bm << 7, n0 = bn << 7;
  const int KT = 24;   // K = 768

  f32x4 acc[4][4] = {};
  const int r0 = tid >> 2, c0 = tid & 3;
  const int r1 = r0 + 64;
  const u16* Wb = wihb + (u64)n0 * 768;
  const int ws0 = r0 * 32 + ((c0 ^ ((r0 >> 1) & 3)) << 3);
  const int ws1 = r1 * 32 + ((c0 ^ ((r1 >> 1) & 3)) << 3);

  auto rowmap = [&](int r) -> int {
    int gr = m0 + r;
    return (gr & 31) * 800 + t0 + (gr >> 5);
  };
  u64 ab0 = 0, ab1 = 0, af0 = 0, af1 = 0;
  if (act){
    ab0 = (u64)rowmap(r0) * 256;  af0 = (u64)rowmap(r0) * 512;
    ab1 = (u64)rowmap(r1) * 256;  af1 = (u64)rowmap(r1) * 512;
  }
  auto aload = [&](u64 rb, u64 rf, int k) -> uint4 {
    if (k >= 256){
      const float* p = memory + rf + (k - 256);
      const float4 a = *(const float4*)p;
      const float4 b = *(const float4*)(p + 4);
      uint4 r;
      r.x = (u32)f2bf(a.x) | ((u32)f2bf(a.y) << 16);
      r.y = (u32)f2bf(a.z) | ((u32)f2bf(a.w) << 16);
      r.z = (u32)f2bf(b.x) | ((u32)f2bf(b.y) << 16);
      r.w = (u32)f2bf(b.z) | ((u32)f2bf(b.w) << 16);
      return r;
    }
    return *(const uint4*)(pn + rb + k);
  };

  uint4 ra0, ra1, rw0, rw1;
  if (act){
    ra0 = aload(ab0, af0, c0 * 8);
    ra1 = aload(ab1, af1, c0 * 8);
    rw0 = *(const uint4*)(Wb + r0 * 768 + c0 * 8);
    rw1 = *(const uint4*)(Wb + r1 * 768 + c0 * 8);
  }
  const int r16 = lane & 15, cg = lane >> 4;

  for (int kt = 0; kt < KT; ++kt){
    if (act){
      *(uint4*)&fs_As[ws0] = ra0;
      *(uint4*)&fs_As[ws1] = ra1;
      *(uint4*)&fs_Ws[ws0] = rw0;
      *(uint4*)&fs_Ws[ws1] = rw1;
    }
    __syncthreads();
    if (act){
      if (kt + 1 < KT){
        const int k0 = ((kt + 1) << 5) + c0 * 8;
        ra0 = aload(ab0, af0, k0);
        ra1 = aload(ab1, af1, k0);
        rw0 = *(const uint4*)(Wb + r0 * 768 + k0);
        rw1 = *(const uint4*)(Wb + r1 * 768 + k0);
      }
      short8 af[4], wf[4];
      #pragma unroll
      for (int mt = 0; mt < 4; ++mt){
        const int row = (wr << 6) + (mt << 4) + r16;
        af[mt] = *(const short8*)&fs_As[(row << 5) + ((cg ^ ((row >> 1) & 3)) << 3)];
      }
      #pragma unroll
      for (int nt = 0; nt < 4; ++nt){
        const int row = (wc << 6) + (nt << 4) + r16;
        wf[nt] = *(const short8*)&fs_Ws[(row << 5) + ((cg ^ ((row >> 1) & 3)) << 3)];
      }
      #pragma unroll
      for (int mt = 0; mt < 4; ++mt)
        #pragma unroll
        for (int nt = 0; nt < 4; ++nt)
          acc[mt][nt] = __builtin_amdgcn_mfma_f32_16x16x32_bf16(af[mt], wf[nt], acc[mt][nt], 0, 0, 0);
    }
    __syncthreads();
  }

  if (act){
    #pragma unroll
    for (int nt = 0; nt < 4; ++nt){
      const int gn = n0 + (wc << 6) + (nt << 4) + r16;
      const float bv = bsum[gn];
      #pragma unroll
      for (int mt = 0; mt < 4; ++mt){
        #pragma unroll
        for (int r = 0; r < 4; ++r){
          const int gm = m0 + (wr << 6) + (mt << 4) + (cg << 2) + r;
          slot[(u64)gm * 4096 + gn] = f2bf(acc[mt][nt][r] + bv);
        }
      }
    }
  }
}

__global__ __launch_bounds__(512, 1) void fused(
    const u16* __restrict__ whhb, const u16* __restrict__ pn,
    const float* __restrict__ memory, const u16* __restrict__ wihb,
    const float* __restrict__ bsum, u16* __restrict__ ring,
    u16* __restrict__ hstep, u32* wflags, u32* pflags, int CT, int nchunks)
{
  const int tid = threadIdx.x;
  const int lane = tid & 63;
  const int wv = tid >> 6;
  const u64 deadline = __builtin_amdgcn_s_memrealtime() + 100000000ull; // ~1s

  if (blockIdx.x >= 64){
    // ----------------------------------------------------------- producer
    const int p = blockIdx.x - 64;   // 0..191
    for (int c = 0; c < nchunks; ++c){
      const int t0 = c * CT;
      const int steps = (800 - t0 < CT) ? (800 - t0) : CT;
      if (c >= 2){
        if (wv == 0){
          const u32 need = (u32)(c - 1);   // all workers entered chunk c-1
          u32 it = 0;
          while (1){
            u32 v = __hip_atomic_load(&wflags[lane << 5], __ATOMIC_RELAXED,
                                      __HIP_MEMORY_SCOPE_AGENT);
            if (__all((int)(v >= need))) break;
            __builtin_amdgcn_s_sleep(8);
            if (((++it) & 15u) == 0u &&
                __builtin_amdgcn_s_memrealtime() > deadline) break;
          }
        }
        __syncthreads();
      }
      const int mt = (steps * 32) >> 7;
      const int TPC = mt * 32;
      u16* slot = ring + (u64)(c & 1) * ((u64)CT << 17);
      for (int tau = p; tau < TPC; tau += 192){
        gemm_tile_512(pn, memory, wihb, bsum, slot, tau % mt, tau / mt, t0);
      }
      __syncthreads();   // all producer stores issued & vmcnt-drained
      if (wv == 0){
        __builtin_amdgcn_fence(__ATOMIC_RELEASE, "agent");  // wb L2 -> MALL
        if (tid == 0)
          __hip_atomic_store(&pflags[p << 5], (u32)(c + 1), __ATOMIC_RELAXED,
                             __HIP_MEMORY_SCOPE_AGENT);
      }
    }
    return;
  }

  // -------------------------------------------------------------- worker
  const int gate = wv & 3, mh = wv >> 2;
  const int u0 = blockIdx.x << 4;
  const int r16 = lane & 15, cg = lane >> 4;

  short8 wf[32];
  {
    const u16* wrow = whhb + (u64)((gate << 10) + u0 + r16) * 1024 + (cg << 3);
    #pragma unroll
    for (int kk = 0; kk < 32; ++kk)
      wf[kk] = *(const short8*)(wrow + (kk << 5));
    #pragma unroll
    for (int kk = 0; kk < 32; ++kk)
      asm volatile("" : "+v"(wf[kk]));
  }

  const int pb = tid >> 4, pu = tid & 15;
  float ccell = 0.f;
  const int arow = (mh << 4) + r16;
  const u16* abase = &fs_hsm[arow << 10];
  const int aswz = (arow & 7) << 3;

  int c = 0, i = 0;
  for (int t = 0; t < 800; ++t, ++i){
    if (i == CT){ c++; i = 0; }
    const bool boundary = (i == 0);
    const u16* gslot = ring + (u64)(c & 1) * ((u64)CT << 17);
    const u64 gb = ((u64)i * 32 + pb) * 4096 + u0 + pu;

    u16 gv0 = 0, gv1 = 0, gv2 = 0, gv3 = 0;
    if (!boundary){   // prefetch (chunk already gated at its first step)
      gv0 = gslot[gb];        gv1 = gslot[gb + 1024];
      gv2 = gslot[gb + 2048]; gv3 = gslot[gb + 3072];
    }
    if (boundary){
      if (wv == 0){
        if (lane == 0)   // chunk-granular progress (paces producer slot reuse)
          __hip_atomic_store(&wflags[blockIdx.x << 5], (u32)c, __ATOMIC_RELAXED,
                             __HIP_MEMORY_SCOPE_AGENT);
        // wait chunk c produced (192 flags, 3 per lane)
        const u32 need = (u32)(c + 1);
        u32 it = 0;
        while (1){
          u32 a = __hip_atomic_load(&pflags[lane << 5], __ATOMIC_RELAXED,
                                    __HIP_MEMORY_SCOPE_AGENT);
          u32 b = __hip_atomic_load(&pflags[(lane + 64) << 5], __ATOMIC_RELAXED,
                                    __HIP_MEMORY_SCOPE_AGENT);
          u32 d = __hip_atomic_load(&pflags[(lane + 128) << 5], __ATOMIC_RELAXED,
                                    __HIP_MEMORY_SCOPE_AGENT);
          u32 m = a < b ? a : b; m = m < d ? m : d;
          if (__all((int)(m >= need))) break;
          if (((++it) & 15u) == 0u &&
              __builtin_amdgcn_s_memrealtime() > deadline) break;
        }
        __builtin_amdgcn_fence(__ATOMIC_ACQUIRE, "agent");  // cached ring reads
      }
      __syncthreads();   // B1 (boundary only)
      gv0 = gslot[gb];        gv1 = gslot[gb + 1024];
      gv2 = gslot[gb + 2048]; gv3 = gslot[gb + 3072];
    }
    // ---- read h_t from hstep[t] with per-thread poison-retry -------------
    u32x4 hr0, hr1, hr2, hr3, hr4, hr5, hr6, hr7;
    {
      const u16* hsrc = hstep + (u64)t * 32768;
      const u32 ob = (u32)tid << 4;
      u32 attempts = 0;
      while (1){
        asm volatile(
          "global_load_dwordx4 %0, %8, %16 sc0 sc1\n\t"
          "global_load_dwordx4 %1, %9, %16 sc0 sc1\n\t"
          "global_load_dwordx4 %2, %10, %16 sc0 sc1\n\t"
          "global_load_dwordx4 %3, %11, %16 sc0 sc1\n\t"
          "global_load_dwordx4 %4, %12, %16 sc0 sc1\n\t"
          "global_load_dwordx4 %5, %13, %16 sc0 sc1\n\t"
          "global_load_dwordx4 %6, %14, %16 sc0 sc1\n\t"
          "global_load_dwordx4 %7, %15, %16 sc0 sc1\n\t"
          "s_waitcnt vmcnt(0)"
          : "=&v"(hr0), "=&v"(hr1), "=&v"(hr2), "=&v"(hr3),
            "=&v"(hr4), "=&v"(hr5), "=&v"(hr6), "=&v"(hr7)
          : "v"(ob), "v"(ob + 8192u), "v"(ob + 16384u), "v"(ob + 24576u),
            "v"(ob + 32768u), "v"(ob + 40960u), "v"(ob + 49152u), "v"(ob + 57344u),
            "s"(hsrc)
          : "memory");
        bool ok = true;
        #pragma unroll
        for (int e = 0; e < 4; ++e){
          ok &= (hr0[e] != POISON); ok &= (hr1[e] != POISON);
          ok &= (hr2[e] != POISON); ok &= (hr3[e] != POISON);
          ok &= (hr4[e] != POISON); ok &= (hr5[e] != POISON);
          ok &= (hr6[e] != POISON); ok &= (hr7[e] != POISON);
        }
        if (ok) break;
        if (((++attempts) & 15u) == 0u &&
            __builtin_amdgcn_s_memrealtime() > deadline) break;
      }
    }
    // stage into LDS, XOR-swizzled
    {
      u32x4 hr[8] = {hr0, hr1, hr2, hr3, hr4, hr5, hr6, hr7};
      #pragma unroll
      for (int j = 0; j < 8; ++j){
        const int ci = (j << 9) + tid;
        const int row = ci >> 7, k16 = ci & 127;
        *(u32x4*)&fs_hsm[(row << 10) + ((k16 ^ (row & 7)) << 3)] = hr[j];
      }
    }
    __syncthreads();   // B2
    f32x4 acc = {};
    #pragma unroll
    for (int kk = 0; kk < 32; ++kk){
      const int k16 = (kk << 2) + cg;
      const short8 af = *(const short8*)&abase[((k16 << 3) ^ aswz)];
      acc = __builtin_amdgcn_mfma_f32_16x16x32_bf16(af, wf[kk], acc, 0, 0, 0);
    }
    #pragma unroll
    for (int r = 0; r < 4; ++r){
      const int m = (mh << 4) + (cg << 2) + r;
      fs_gsm[(gate << 9) + (m << 4) + r16] = acc[r];
    }
    __syncthreads();   // B3
    {
      const int o = (pb << 4) + pu;
      const float gi = fs_gsm[o]        + bf2f(gv0);
      const float gf = fs_gsm[512 + o]  + bf2f(gv1);
      const float gg = fs_gsm[1024 + o] + bf2f(gv2);
      const float go = fs_gsm[1536 + o] + bf2f(gv3);
      ccell = sigf(gf) * ccell + sigf(gi) * tanh_(gg);
      const float h = sigf(go) * tanh_(ccell);
      const u16 hbits = f2bf(h);
      // publish h_{t+1} -> hstep[t+1]: packed pair, relaxed agent atomic.
      // This IS the history write (projection reads hstep via OMAP).
      const u32 other = (u32)(u16)__shfl_xor((int)(u32)hbits, 1);
      if ((tid & 1) == 0){
        const u32 w = ((u32)hbits) | (other << 16);
        u32* dst = (u32*)(void*)hstep +
                   ((u64)(t + 1) * 16384 + (pb << 9) + (u0 >> 1) + (pu >> 1));
        __hip_atomic_store(dst, w, __ATOMIC_RELAXED, __HIP_MEMORY_SCOPE_AGENT);
      }
    }
    // no B4, no step flag — next iteration's poison-retry is the sync.
  }
}

// -------------------------------------------------------------------- launch

extern "C" void kernel_launch(void* const* d_in, const int* in_sizes, int n_in,
                              void* d_out, int out_size, void* d_ws, size_t ws_size,
                              hipStream_t stream){
  const float* memory = (const float*)d_in[0];
  const float* ymels  = (const float*)d_in[1];
  const float* w1     = (const float*)d_in[2];
  const float* w2     = (const float*)d_in[3];
  const float* wih    = (const float*)d_in[4];
  const float* whh    = (const float*)d_in[5];
  const float* bih    = (const float*)d_in[6];
  const float* bhh    = (const float*)d_in[7];
  const float* pw     = (const float*)d_in[8];
  const float* pbias  = (const float*)d_in[9];
  float* out = (float*)d_out;

  char* ws = (char*)d_ws;
  u64 off = 0;
  auto alloc = [&](u64 bytes) -> void* {
    void* p = ws + off;
    off += (bytes + 255) & ~255ull;
    return p;
  };
  u16* hstep = (u16*)alloc((u64)801 * 32768 * 2);   // 52.5 MB (h per step; history)
  u16* pn    = (u16*)alloc((u64)ROWS * 256 * 2);    // 13.1 MB
  u16* wihb  = (u16*)alloc((u64)4096 * 768 * 2);    // 6.3 MB
  u16* whhb  = (u16*)alloc((u64)4096 * 1024 * 2);   // 8.4 MB
  u16* w1p   = (u16*)alloc(256 * 96 * 2);
  u16* w2b   = (u16*)alloc(256 * 256 * 2);
  u16* projp = (u16*)alloc(128 * 1536 * 2);
  float* bsum = (float*)alloc(4096 * 4);
  u32* wflags = (u32*)alloc(64 * 32 * 4);
  u32* pflags = (u32*)alloc(192 * 32 * 4);
  // prenet temporaries alias hstep (dead before the fused kernel's initk? no —
  // initk poisons hstep BEFORE prenet runs; prenet temporaries must not alias
  // hstep). Use separate small allocs instead.
  u16* prevp = (u16*)alloc((u64)ROWS * 96 * 2);     // 4.9 MB
  u16* h1b   = (u16*)alloc((u64)ROWS * 256 * 2);    // 13.1 MB

  int CT = 0;
  u16* ring = (u16*)(ws + off);
  if (ws_size > off){
    u64 avail = ws_size - off;
    CT = (int)(avail / (2ull * 32 * 4096 * 2));
    CT &= ~3;
    if (CT > 64) CT = 64;
  }
  if (CT < 8){
    float val = 1.0e6f + 10.0f * (float)(ws_size >> 20);
    sentinel_fill<<<256, 256, 0, stream>>>(out, out_size, val);
    return;
  }
  const int nchunks = (800 + CT - 1) / CT;

  initk<<<256, 256, 0, stream>>>(wflags, pflags, (u32*)(void*)hstep);
  prep_prev<<<(ROWS * 96) / 256, 256, 0, stream>>>(ymels, prevp);
  prep_w<<<(256*96 + 256*256 + 4096*768 + 128*1536 + 4096 + 4096*1024 + 255) / 256,
           256, 0, stream>>>(
      w1, w2, wih, pw, bih, bhh, whh, w1p, w2b, wihb, projp, bsum, whhb);

  // prenet layer 1: h1 = relu(prev @ w1^T)
  gemm_tn<1,0,0,0,0,0,0><<<200 * 2, 256, 0, stream>>>(prevp, nullptr, w1p, h1b, nullptr,
      ROWS, 96, 96, 0, 96, 256, 256, 0, 0);
  // prenet layer 2 -> pn (row stride 256)
  gemm_tn<1,0,0,0,0,0,0><<<200 * 2, 256, 0, stream>>>(h1b, nullptr, w2b, pn, nullptr,
      ROWS, 256, 256, 0, 256, 256, 256, 0, 0);

  // fused: producers (gates GEMM -> ring) + workers (LSTM recurrence)
  fused<<<256, 512, 0, stream>>>(whhb, pn, memory, wihb, bsum, ring,
                                 hstep, wflags, pflags, CT, nchunks);

  // projection: mel = [h|memory] @ proj_w^T + proj_b
  // A = hstep slots 1..800, t-major rows (gr = t*32 + b -> addr gr*1024);
  // A2 = memory (b-major, A2MAP); C = out (b-major, OMAP).
  gemm_tn<0,1,1,0,1,1,1><<<200 * 1, 256, 0, stream>>>(hstep + 32768, memory, projp,
      out, pbias, ROWS, 1536, 1024, 512, 1536, 80, 80, 1024, 0);
}

// Round 15
// 3569.644 us; speedup vs baseline: 1.1848x; 1.1848x over previous
//
#include <hip/hip_runtime.h>
#include <hip/hip_bf16.h>

typedef unsigned short u16;
typedef unsigned int u32;
typedef unsigned long long u64;
typedef __attribute__((ext_vector_type(8))) short short8;
typedef __attribute__((ext_vector_type(4))) float f32x4;
typedef __attribute__((ext_vector_type(4))) u32 u32x4;

#define ROWS 25600  // B*T = 32*800

__device__ __forceinline__ u16 f2bf(float f){
  u32 x = __builtin_bit_cast(u32, f);
  u32 r = (x + 0x7FFFu + ((x >> 16) & 1u)) >> 16;
  return (u16)r;
}
__device__ __forceinline__ float bf2f(u16 h){
  return __builtin_bit_cast(float, ((u32)h) << 16);
}
__device__ __forceinline__ float sigf(float x){
  x = fminf(fmaxf(x, -30.f), 30.f);
  return 1.f / (1.f + __expf(-x));
}
__device__ __forceinline__ float tanh_(float x){
  x = fminf(fmaxf(x, -15.f), 15.f);
  float e = __expf(-2.f * x);
  return (1.f - e) / (1.f + e);
}

// ---------------------------------------------------------------- init / prep

__global__ void initk(u32* wflags, u32* pflags, u16* hb){
  int i = blockIdx.x * blockDim.x + threadIdx.x;
  int stride = blockDim.x * gridDim.x;
  for (int j = i; j < 64 * 32; j += stride) wflags[j] = 0;
  for (int j = i; j < 192 * 32; j += stride) pflags[j] = 0;
  for (int j = i; j < 2 * 32 * 1024; j += stride) hb[j] = 0;
}

__global__ void sentinel_fill(float* out, int n, float val){
  for (int i = blockIdx.x * blockDim.x + threadIdx.x; i < n;
       i += blockDim.x * gridDim.x)
    out[i] = val;
}

__global__ void prep_prev(const float* __restrict__ ym, u16* __restrict__ prevp){
  int idx = blockIdx.x * blockDim.x + threadIdx.x;
  if (idx >= ROWS * 96) return;
  int r = idx / 96, c = idx - r * 96;
  int b = r / 800, t = r - b * 800;
  float v = 0.f;
  if (c < 80 && t > 0) v = ym[(u64)(b * 800 + (t - 1)) * 80 + c];
  prevp[idx] = f2bf(v);
}

__global__ void prep_w(const float* __restrict__ w1, const float* __restrict__ w2,
                       const float* __restrict__ wih, const float* __restrict__ pw,
                       const float* __restrict__ bih, const float* __restrict__ bhh,
                       const float* __restrict__ whh,
                       u16* __restrict__ w1p, u16* __restrict__ w2b,
                       u16* __restrict__ wihb, u16* __restrict__ projp,
                       float* __restrict__ bsum, u16* __restrict__ whhb){
  int idx = blockIdx.x * blockDim.x + threadIdx.x;
  const int n1 = 256 * 96, n2 = 256 * 256, n3 = 4096 * 768, n4 = 128 * 1536, n5 = 4096;
  const int n6 = 4096 * 1024;
  if (idx < n1){
    int r = idx / 96, c = idx - r * 96;
    w1p[idx] = (c < 80) ? f2bf(w1[r * 80 + c]) : (u16)0;
  } else if ((idx -= n1) < n2){
    w2b[idx] = f2bf(w2[idx]);
  } else if ((idx -= n2) < n3){
    wihb[idx] = f2bf(wih[idx]);
  } else if ((idx -= n3) < n4){
    int r = idx / 1536;
    projp[idx] = (r < 80) ? f2bf(pw[idx]) : (u16)0;
  } else if ((idx -= n4) < n5){
    bsum[idx] = bih[idx] + bhh[idx];
  } else if ((idx -= n5) < n6){
    whhb[idx] = f2bf(whh[idx]);
  }
}

// ------------------------------------------------------------ generic TN GEMM
// (standalone; used for prenet + projection)

template<int RELU, int OUTF32, int HASBIAS, int AMAP, int SPLIT>
__global__ __launch_bounds__(256, 2) void gemm_tn(
    const u16* __restrict__ A, const float* __restrict__ A2,
    const u16* __restrict__ W, void* __restrict__ Cv,
    const float* __restrict__ bias,
    int M, int K, int lda, int lda2, int ldw, int ldc, int nmax,
    int ksplit, int t0)
{
  __shared__ __align__(16) u16 As[128 * 32];
  __shared__ __align__(16) u16 Ws[128 * 32];
  const int tid = threadIdx.x;
  const int lane = tid & 63;
  const int wv = tid >> 6;
  const int wr = wv & 1, wc = wv >> 1;
  const int mtiles = M >> 7;
  const int ntiles = gridDim.x / mtiles;
  int bm, bn;
  if (mtiles & 7){
    bm = blockIdx.x % mtiles;
    bn = blockIdx.x / mtiles;
  } else {
    int per = 8 * ntiles;
    int g = blockIdx.x / per, rem = blockIdx.x % per;
    bm = g * 8 + (rem & 7);
    bn = rem >> 3;
  }
  const int m0 = bm << 7, n0 = bn << 7;
  const int KT = K >> 5;

  f32x4 acc[4][4] = {};

  const int r0 = tid >> 2, c0 = tid & 3;
  const int r1 = r0 + 64;
  const u16* Wb = W + (u64)n0 * ldw;
  const int ws0 = r0 * 32 + ((c0 ^ ((r0 >> 1) & 3)) << 3);
  const int ws1 = r1 * 32 + ((c0 ^ ((r1 >> 1) & 3)) << 3);

  auto rowmap = [&](int r) -> int {
    int gr = m0 + r;
    if (AMAP) return (gr & 31) * 800 + t0 + (gr >> 5);
    return gr;
  };
  const u64 ab0 = (u64)rowmap(r0) * lda;
  const u64 ab1 = (u64)rowmap(r1) * lda;
  const u64 af0 = SPLIT ? (u64)rowmap(r0) * lda2 : 0;
  const u64 af1 = SPLIT ? (u64)rowmap(r1) * lda2 : 0;

  auto aload = [&](u64 rb, u64 rf, int k) -> uint4 {
    if (SPLIT && k >= ksplit){
      const float* p = A2 + rf + (k - ksplit);
      const float4 a = *(const float4*)p;
      const float4 b = *(const float4*)(p + 4);
      uint4 r;
      r.x = (u32)f2bf(a.x) | ((u32)f2bf(a.y) << 16);
      r.y = (u32)f2bf(a.z) | ((u32)f2bf(a.w) << 16);
      r.z = (u32)f2bf(b.x) | ((u32)f2bf(b.y) << 16);
      r.w = (u32)f2bf(b.z) | ((u32)f2bf(b.w) << 16);
      return r;
    }
    return *(const uint4*)(A + rb + k);
  };

  uint4 ra0 = aload(ab0, af0, c0 * 8);
  uint4 ra1 = aload(ab1, af1, c0 * 8);
  uint4 rw0 = *(const uint4*)(Wb + r0 * ldw + c0 * 8);
  uint4 rw1 = *(const uint4*)(Wb + r1 * ldw + c0 * 8);

  const int r16 = lane & 15, cg = lane >> 4;

  for (int kt = 0; kt < KT; ++kt){
    *(uint4*)&As[ws0] = ra0;
    *(uint4*)&As[ws1] = ra1;
    *(uint4*)&Ws[ws0] = rw0;
    *(uint4*)&Ws[ws1] = rw1;
    __syncthreads();
    if (kt + 1 < KT){
      const int k0 = ((kt + 1) << 5) + c0 * 8;
      ra0 = aload(ab0, af0, k0);
      ra1 = aload(ab1, af1, k0);
      rw0 = *(const uint4*)(Wb + r0 * ldw + k0);
      rw1 = *(const uint4*)(Wb + r1 * ldw + k0);
    }
    short8 af[4], wf[4];
    #pragma unroll
    for (int mt = 0; mt < 4; ++mt){
      const int row = (wr << 6) + (mt << 4) + r16;
      af[mt] = *(const short8*)&As[(row << 5) + ((cg ^ ((row >> 1) & 3)) << 3)];
    }
    #pragma unroll
    for (int nt = 0; nt < 4; ++nt){
      const int row = (wc << 6) + (nt << 4) + r16;
      wf[nt] = *(const short8*)&Ws[(row << 5) + ((cg ^ ((row >> 1) & 3)) << 3)];
    }
    #pragma unroll
    for (int mt = 0; mt < 4; ++mt)
      #pragma unroll
      for (int nt = 0; nt < 4; ++nt)
        acc[mt][nt] = __builtin_amdgcn_mfma_f32_16x16x32_bf16(af[mt], wf[nt], acc[mt][nt], 0, 0, 0);
    __syncthreads();
  }

  #pragma unroll
  for (int nt = 0; nt < 4; ++nt){
    const int gn = n0 + (wc << 6) + (nt << 4) + r16;
    if (gn < nmax){
      float bv = 0.f;
      if (HASBIAS) bv = bias[gn];
      #pragma unroll
      for (int mt = 0; mt < 4; ++mt){
        #pragma unroll
        for (int r = 0; r < 4; ++r){
          const int gm = m0 + (wr << 6) + (mt << 4) + (cg << 2) + r;
          float v = acc[mt][nt][r] + bv;
          if (RELU) v = fmaxf(v, 0.f);
          if (OUTF32) ((float*)Cv)[(u64)gm * ldc + gn] = v;
          else        ((u16*)Cv)[(u64)gm * ldc + gn] = f2bf(v);
        }
      }
    }
  }
}

// ==================== fused persistent producer/consumer kernel ==============
// grid = 256 x 512 threads, 1 WG/CU (88KB LDS).
//   blockIdx 0..63   : LSTM workers.
//   blockIdx 64..255 : producers — gates GEMM chunk-by-chunk into 2-slot ring.
// r15 protocol (r13 + barrier elimination):
//   - h publish = packed-u32 relaxed AGENT atomics (MALL-serialized)
//   - h read = coalesced global_load_dwordx4 sc0+sc1 (MALL-coherent), no fence
//   - flag publish PER-WAVE: each wave drains its own h stores (vmcnt(0)),
//     bumps an LDS counter; 8th wave stores the WG flag (r9-validated).
//   - ALL 8 waves poll the 64 WG flags; own-flag inclusion makes the poll the
//     local barrier -> B1 and B4 gone; 2 barriers/step (B2, B3).

__shared__ __align__(16) u16 fs_hsm[32 * 1024];  // 64KB worker h tile
__shared__ __align__(16) float fs_gsm[2048];     // 8KB worker gate exchange
__shared__ __align__(16) u16 fs_As[128 * 32];    // 8KB producer A tile
__shared__ __align__(16) u16 fs_Ws[128 * 32];    // 8KB producer W tile
__shared__ u32 fs_done;                          // per-WG wave-completion counter

__device__ void gemm_tile_512(
    const u16* __restrict__ pn, const float* __restrict__ memory,
    const u16* __restrict__ wihb, const float* __restrict__ bsum,
    u16* __restrict__ slot, int bm, int bn, int t0)
{
  const int tid = threadIdx.x;
  const bool act = (tid < 256);
  const int lane = tid & 63;
  const int wv4 = (tid >> 6) & 3;
  const int wr = wv4 & 1, wc = wv4 >> 1;
  const int m0 = bm << 7, n0 = bn << 7;
  const int KT = 24;   // K = 768

  f32x4 acc[4][4] = {};
  const int r0 = tid >> 2, c0 = tid & 3;
  const int r1 = r0 + 64;
  const u16* Wb = wihb + (u64)n0 * 768;
  const int ws0 = r0 * 32 + ((c0 ^ ((r0 >> 1) & 3)) << 3);
  const int ws1 = r1 * 32 + ((c0 ^ ((r1 >> 1) & 3)) << 3);

  auto rowmap = [&](int r) -> int {
    int gr = m0 + r;
    return (gr & 31) * 800 + t0 + (gr >> 5);
  };
  u64 ab0 = 0, ab1 = 0, af0 = 0, af1 = 0;
  if (act){
    ab0 = (u64)rowmap(r0) * 256;  af0 = (u64)rowmap(r0) * 512;
    ab1 = (u64)rowmap(r1) * 256;  af1 = (u64)rowmap(r1) * 512;
  }
  auto aload = [&](u64 rb, u64 rf, int k) -> uint4 {
    if (k >= 256){
      const float* p = memory + rf + (k - 256);
      const float4 a = *(const float4*)p;
      const float4 b = *(const float4*)(p + 4);
      uint4 r;
      r.x = (u32)f2bf(a.x) | ((u32)f2bf(a.y) << 16);
      r.y = (u32)f2bf(a.z) | ((u32)f2bf(a.w) << 16);
      r.z = (u32)f2bf(b.x) | ((u32)f2bf(b.y) << 16);
      r.w = (u32)f2bf(b.z) | ((u32)f2bf(b.w) << 16);
      return r;
    }
    return *(const uint4*)(pn + rb + k);
  };

  uint4 ra0, ra1, rw0, rw1;
  if (act){
    ra0 = aload(ab0, af0, c0 * 8);
    ra1 = aload(ab1, af1, c0 * 8);
    rw0 = *(const uint4*)(Wb + r0 * 768 + c0 * 8);
    rw1 = *(const uint4*)(Wb + r1 * 768 + c0 * 8);
  }
  const int r16 = lane & 15, cg = lane >> 4;

  for (int kt = 0; kt < KT; ++kt){
    if (act){
      *(uint4*)&fs_As[ws0] = ra0;
      *(uint4*)&fs_As[ws1] = ra1;
      *(uint4*)&fs_Ws[ws0] = rw0;
      *(uint4*)&fs_Ws[ws1] = rw1;
    }
    __syncthreads();
    if (act){
      if (kt + 1 < KT){
        const int k0 = ((kt + 1) << 5) + c0 * 8;
        ra0 = aload(ab0, af0, k0);
        ra1 = aload(ab1, af1, k0);
        rw0 = *(const uint4*)(Wb + r0 * 768 + k0);
        rw1 = *(const uint4*)(Wb + r1 * 768 + k0);
      }
      short8 af[4], wf[4];
      #pragma unroll
      for (int mt = 0; mt < 4; ++mt){
        const int row = (wr << 6) + (mt << 4) + r16;
        af[mt] = *(const short8*)&fs_As[(row << 5) + ((cg ^ ((row >> 1) & 3)) << 3)];
      }
      #pragma unroll
      for (int nt = 0; nt < 4; ++nt){
        const int row = (wc << 6) + (nt << 4) + r16;
        wf[nt] = *(const short8*)&fs_Ws[(row << 5) + ((cg ^ ((row >> 1) & 3)) << 3)];
      }
      #pragma unroll
      for (int mt = 0; mt < 4; ++mt)
        #pragma unroll
        for (int nt = 0; nt < 4; ++nt)
          acc[mt][nt] = __builtin_amdgcn_mfma_f32_16x16x32_bf16(af[mt], wf[nt], acc[mt][nt], 0, 0, 0);
    }
    __syncthreads();
  }

  if (act){
    #pragma unroll
    for (int nt = 0; nt < 4; ++nt){
      const int gn = n0 + (wc << 6) + (nt << 4) + r16;
      const float bv = bsum[gn];
      #pragma unroll
      for (int mt = 0; mt < 4; ++mt){
        #pragma unroll
        for (int r = 0; r < 4; ++r){
          const int gm = m0 + (wr << 6) + (mt << 4) + (cg << 2) + r;
          slot[(u64)gm * 4096 + gn] = f2bf(acc[mt][nt][r] + bv);
        }
      }
    }
  }
}

__global__ __launch_bounds__(512, 1) void fused(
    const u16* __restrict__ whhb, const u16* __restrict__ pn,
    const float* __restrict__ memory, const u16* __restrict__ wihb,
    const float* __restrict__ bsum, u16* __restrict__ ring,
    u16* __restrict__ hb, u16* __restrict__ hs,
    u32* wflags, u32* pflags, int CT, int nchunks)
{
  const int tid = threadIdx.x;
  const int lane = tid & 63;
  const int wv = tid >> 6;
  const u64 deadline = __builtin_amdgcn_s_memrealtime() + 100000000ull; // ~1s

  if (blockIdx.x >= 64){
    // ----------------------------------------------------------- producer
    const int p = blockIdx.x - 64;   // 0..191
    for (int c = 0; c < nchunks; ++c){
      const int t0 = c * CT;
      const int steps = (800 - t0 < CT) ? (800 - t0) : CT;
      if (c >= 2){
        if (wv == 0){
          const u32 need = (u32)((c - 1) * CT);
          u32 it = 0;
          while (1){
            u32 v = __hip_atomic_load(&wflags[lane << 5], __ATOMIC_RELAXED,
                                      __HIP_MEMORY_SCOPE_AGENT);
            if (__all((int)(v >= need))) break;
            __builtin_amdgcn_s_sleep(8);
            if (((++it) & 15u) == 0u &&
                __builtin_amdgcn_s_memrealtime() > deadline) break;
          }
        }
        __syncthreads();
      }
      const int mt = (steps * 32) >> 7;
      const int TPC = mt * 32;
      u16* slot = ring + (u64)(c & 1) * ((u64)CT << 17);
      for (int tau = p; tau < TPC; tau += 192){
        gemm_tile_512(pn, memory, wihb, bsum, slot, tau % mt, tau / mt, t0);
      }
      __syncthreads();   // all producer stores issued & vmcnt-drained
      if (wv == 0){
        __builtin_amdgcn_fence(__ATOMIC_RELEASE, "agent");  // wb L2 -> MALL
        if (tid == 0)
          __hip_atomic_store(&pflags[p << 5], (u32)(c + 1), __ATOMIC_RELAXED,
                             __HIP_MEMORY_SCOPE_AGENT);
      }
    }
    return;
  }

  // -------------------------------------------------------------- worker
  const int gate = wv & 3, mh = wv >> 2;
  const int u0 = blockIdx.x << 4;
  const int r16 = lane & 15, cg = lane >> 4;

  if (tid == 0) fs_done = 0;

  short8 wf[32];
  {
    const u16* wrow = whhb + (u64)((gate << 10) + u0 + r16) * 1024 + (cg << 3);
    #pragma unroll
    for (int kk = 0; kk < 32; ++kk)
      wf[kk] = *(const short8*)(wrow + (kk << 5));
    #pragma unroll
    for (int kk = 0; kk < 32; ++kk)
      asm volatile("" : "+v"(wf[kk]));
  }
  __syncthreads();   // fs_done init visible

  const int pb = tid >> 4, pu = tid & 15;
  float ccell = 0.f;
  const int arow = (mh << 4) + r16;
  const u16* abase = &fs_hsm[arow << 10];
  const int aswz = (arow & 7) << 3;

  int c = 0, i = 0;
  for (int t = 0; t < 800; ++t, ++i){
    if (i == CT){ c++; i = 0; }
    const bool boundary = (i == 0);
    const u16* gslot = ring + (u64)(c & 1) * ((u64)CT << 17);
    const u64 gb = ((u64)i * 32 + pb) * 4096 + u0 + pu;
    const int cur = t & 1;

    u16 gv0 = 0, gv1 = 0, gv2 = 0, gv3 = 0;
    if (!boundary){   // prefetch (chunk already gated at its first step)
      gv0 = gslot[gb];        gv1 = gslot[gb + 1024];
      gv2 = gslot[gb + 2048]; gv3 = gslot[gb + 3072];
    }
    if (boundary){   // producer-chunk gate (13x total): wave0 + fence + barrier
      if (wv == 0){
        const u32 need = (u32)(c + 1);
        u32 it = 0;
        while (1){
          u32 a = __hip_atomic_load(&pflags[lane << 5], __ATOMIC_RELAXED,
                                    __HIP_MEMORY_SCOPE_AGENT);
          u32 b = __hip_atomic_load(&pflags[(lane + 64) << 5], __ATOMIC_RELAXED,
                                    __HIP_MEMORY_SCOPE_AGENT);
          u32 d = __hip_atomic_load(&pflags[(lane + 128) << 5], __ATOMIC_RELAXED,
                                    __HIP_MEMORY_SCOPE_AGENT);
          u32 m = a < b ? a : b; m = m < d ? m : d;
          if (__all((int)(m >= need))) break;
          if (((++it) & 15u) == 0u &&
              __builtin_amdgcn_s_memrealtime() > deadline) break;
        }
        __builtin_amdgcn_fence(__ATOMIC_ACQUIRE, "agent");  // cached ring reads
      }
      __syncthreads();
      gv0 = gslot[gb];        gv1 = gslot[gb + 1024];
      gv2 = gslot[gb + 2048]; gv3 = gslot[gb + 3072];
    }
    // step gate: ALL waves poll the 64 WG flags (own flag => local barrier)
    if (t > 0){
      u32 it = 0;
      while (1){
        u32 v = __hip_atomic_load(&wflags[lane << 5], __ATOMIC_RELAXED,
                                  __HIP_MEMORY_SCOPE_AGENT);
        if (__all((int)(v >= (u32)t))) break;
        if (((++it) & 15u) == 0u &&
            __builtin_amdgcn_s_memrealtime() > deadline) break;
      }
    }
    // stage h_t (64KB) into LDS via MALL-coherent coalesced sc0+sc1 reads
    {
      const u16* hsrc = hb + cur * 32768;
      u32x4 hr[8];
      {
        u32x4 h0,h1,h2,h3,h4,h5,h6,h7;
        const u32 ob = (u32)tid << 4;
        asm volatile(
          "global_load_dwordx4 %0, %8, %16 sc0 sc1\n\t"
          "global_load_dwordx4 %1, %9, %16 sc0 sc1\n\t"
          "global_load_dwordx4 %2, %10, %16 sc0 sc1\n\t"
          "global_load_dwordx4 %3, %11, %16 sc0 sc1\n\t"
          "global_load_dwordx4 %4, %12, %16 sc0 sc1\n\t"
          "global_load_dwordx4 %5, %13, %16 sc0 sc1\n\t"
          "global_load_dwordx4 %6, %14, %16 sc0 sc1\n\t"
          "global_load_dwordx4 %7, %15, %16 sc0 sc1\n\t"
          "s_waitcnt vmcnt(0)"
          : "=&v"(h0), "=&v"(h1), "=&v"(h2), "=&v"(h3),
            "=&v"(h4), "=&v"(h5), "=&v"(h6), "=&v"(h7)
          : "v"(ob), "v"(ob + 8192u), "v"(ob + 16384u), "v"(ob + 24576u),
            "v"(ob + 32768u), "v"(ob + 40960u), "v"(ob + 49152u), "v"(ob + 57344u),
            "s"(hsrc)
          : "memory");
        __builtin_amdgcn_sched_barrier(0);
        hr[0]=h0; hr[1]=h1; hr[2]=h2; hr[3]=h3;
        hr[4]=h4; hr[5]=h5; hr[6]=h6; hr[7]=h7;
      }
      #pragma unroll
      for (int j = 0; j < 8; ++j){
        const int ci = (j << 9) + tid;
        const int row = ci >> 7, k16 = ci & 127;
        *(u32x4*)&fs_hsm[(row << 10) + ((k16 ^ (row & 7)) << 3)] = hr[j];
      }
    }
    __syncthreads();   // B2
    f32x4 acc = {};
    #pragma unroll
    for (int kk = 0; kk < 32; ++kk){
      const int k16 = (kk << 2) + cg;
      const short8 af = *(const short8*)&abase[((k16 << 3) ^ aswz)];
      acc = __builtin_amdgcn_mfma_f32_16x16x32_bf16(af, wf[kk], acc, 0, 0, 0);
    }
    #pragma unroll
    for (int r = 0; r < 4; ++r){
      const int m = (mh << 4) + (cg << 2) + r;
      fs_gsm[(gate << 9) + (m << 4) + r16] = acc[r];
    }
    __syncthreads();   // B3
    u16 hbits;
    {
      const int o = (pb << 4) + pu;
      const float gi = fs_gsm[o]        + bf2f(gv0);
      const float gf = fs_gsm[512 + o]  + bf2f(gv1);
      const float gg = fs_gsm[1024 + o] + bf2f(gv2);
      const float go = fs_gsm[1536 + o] + bf2f(gv3);
      ccell = sigf(gf) * ccell + sigf(gi) * tanh_(gg);
      const float h = sigf(go) * tanh_(ccell);
      hbits = f2bf(h);
      // publish h: packed pair -> relaxed agent atomic (MALL-serialized)
      const u32 other = (u32)(u16)__shfl_xor((int)(u32)hbits, 1);
      if ((tid & 1) == 0){
        const u32 w = ((u32)hbits) | (other << 16);
        u32* dst = (u32*)(void*)hb + ((cur ^ 1) * 16384 + (pb << 9) + (u0 >> 1) + (pu >> 1));
        __hip_atomic_store(dst, w, __ATOMIC_RELAXED, __HIP_MEMORY_SCOPE_AGENT);
      }
    }
    // per-wave ordered flag publish (replaces B4 + tid0 funnel):
    // drain own h stores -> LDS counter -> 8th wave stores the WG flag.
    asm volatile("s_waitcnt vmcnt(0)" ::: "memory");
    if (lane == 0){
      u32 old = __hip_atomic_fetch_add(&fs_done, 1u, __ATOMIC_RELAXED,
                                       __HIP_MEMORY_SCOPE_WORKGROUP);
      if (old == (u32)(8 * t + 7))
        __hip_atomic_store(&wflags[blockIdx.x << 5], (u32)(t + 1), __ATOMIC_RELAXED,
                           __HIP_MEMORY_SCOPE_AGENT);
    }
    // hs history store after flag path (drains under the next step)
    hs[(((u64)pb * 800 + t) << 10) + u0 + pu] = hbits;
  }
}

// -------------------------------------------------------------------- launch

extern "C" void kernel_launch(void* const* d_in, const int* in_sizes, int n_in,
                              void* d_out, int out_size, void* d_ws, size_t ws_size,
                              hipStream_t stream){
  const float* memory = (const float*)d_in[0];
  const float* ymels  = (const float*)d_in[1];
  const float* w1     = (const float*)d_in[2];
  const float* w2     = (const float*)d_in[3];
  const float* wih    = (const float*)d_in[4];
  const float* whh    = (const float*)d_in[5];
  const float* bih    = (const float*)d_in[6];
  const float* bhh    = (const float*)d_in[7];
  const float* pw     = (const float*)d_in[8];
  const float* pbias  = (const float*)d_in[9];
  float* out = (float*)d_out;

  char* ws = (char*)d_ws;
  u64 off = 0;
  auto alloc = [&](u64 bytes) -> void* {
    void* p = ws + off;
    off += (bytes + 255) & ~255ull;
    return p;
  };
  u16* hs    = (u16*)alloc((u64)ROWS * 1024 * 2);   // 52.4 MB
  u16* pn    = (u16*)alloc((u64)ROWS * 256 * 2);    // 13.1 MB
  u16* wihb  = (u16*)alloc((u64)4096 * 768 * 2);    // 6.3 MB
  u16* whhb  = (u16*)alloc((u64)4096 * 1024 * 2);   // 8.4 MB
  u16* w1p   = (u16*)alloc(256 * 96 * 2);
  u16* w2b   = (u16*)alloc(256 * 256 * 2);
  u16* projp = (u16*)alloc(128 * 1536 * 2);
  float* bsum = (float*)alloc(4096 * 4);
  u16* hb    = (u16*)alloc(2 * 32768 * 2);
  u32* wflags = (u32*)alloc(64 * 32 * 4);
  u32* pflags = (u32*)alloc(192 * 32 * 4);
  u16* prevp = hs;                   // aliases (dead before hs written)
  u16* h1b   = hs + (8u << 20);

  int CT = 0;
  u16* ring = (u16*)(ws + off);
  if (ws_size > off){
    u64 avail = ws_size - off;
    CT = (int)(avail / (2ull * 32 * 4096 * 2));
    CT &= ~3;
    if (CT > 64) CT = 64;
  }
  if (CT < 8){
    float val = 1.0e6f + 10.0f * (float)(ws_size >> 20);
    sentinel_fill<<<256, 256, 0, stream>>>(out, out_size, val);
    return;
  }
  const int nchunks = (800 + CT - 1) / CT;

  initk<<<64, 256, 0, stream>>>(wflags, pflags, hb);
  prep_prev<<<(ROWS * 96) / 256, 256, 0, stream>>>(ymels, prevp);
  prep_w<<<(256*96 + 256*256 + 4096*768 + 128*1536 + 4096 + 4096*1024 + 255) / 256,
           256, 0, stream>>>(
      w1, w2, wih, pw, bih, bhh, whh, w1p, w2b, wihb, projp, bsum, whhb);

  // prenet layer 1: h1 = relu(prev @ w1^T)
  gemm_tn<1,0,0,0,0><<<200 * 2, 256, 0, stream>>>(prevp, nullptr, w1p, h1b, nullptr,
      ROWS, 96, 96, 0, 96, 256, 256, 0, 0);
  // prenet layer 2 -> pn (row stride 256)
  gemm_tn<1,0,0,0,0><<<200 * 2, 256, 0, stream>>>(h1b, nullptr, w2b, pn, nullptr,
      ROWS, 256, 256, 0, 256, 256, 256, 0, 0);

  // fused: producers (gates GEMM -> ring) + consumers (LSTM recurrence)
  fused<<<256, 512, 0, stream>>>(whhb, pn, memory, wihb, bsum, ring, hb, hs,
                                 wflags, pflags, CT, nchunks);

  // projection: mel = [hs|memory] @ proj_w^T + proj_b
  gemm_tn<0,1,1,0,1><<<200 * 1, 256, 0, stream>>>(hs, memory, projp, out, pbias,
      ROWS, 1536, 1024, 512, 1536, 80, 80, 1024, 0);
}

// Round 16
// 2874.597 us; speedup vs baseline: 1.4712x; 1.2418x over previous
//
#include <hip/hip_runtime.h>
#include <hip/hip_bf16.h>

typedef unsigned short u16;
typedef unsigned int u32;
typedef unsigned long long u64;
typedef __attribute__((ext_vector_type(8))) short short8;
typedef __attribute__((ext_vector_type(4))) float f32x4;
typedef __attribute__((ext_vector_type(4))) u32 u32x4;

#define ROWS 25600  // B*T = 32*800

__device__ __forceinline__ u16 f2bf(float f){
  u32 x = __builtin_bit_cast(u32, f);
  u32 r = (x + 0x7FFFu + ((x >> 16) & 1u)) >> 16;
  return (u16)r;
}
__device__ __forceinline__ float bf2f(u16 h){
  return __builtin_bit_cast(float, ((u32)h) << 16);
}
__device__ __forceinline__ float sigf(float x){
  x = fminf(fmaxf(x, -30.f), 30.f);
  return 1.f / (1.f + __expf(-x));
}
__device__ __forceinline__ float tanh_(float x){
  x = fminf(fmaxf(x, -15.f), 15.f);
  float e = __expf(-2.f * x);
  return (1.f - e) / (1.f + e);
}

// ---------------------------------------------------------------- init / prep

__global__ void initk(u32* wflags, u32* pflags, u16* hb){
  int i = blockIdx.x * blockDim.x + threadIdx.x;
  int stride = blockDim.x * gridDim.x;
  for (int j = i; j < 64 * 32; j += stride) wflags[j] = 0;
  for (int j = i; j < 192 * 32; j += stride) pflags[j] = 0;
  for (int j = i; j < 2 * 32 * 1024; j += stride) hb[j] = 0;
}

__global__ void sentinel_fill(float* out, int n, float val){
  for (int i = blockIdx.x * blockDim.x + threadIdx.x; i < n;
       i += blockDim.x * gridDim.x)
    out[i] = val;
}

__global__ void prep_prev(const float* __restrict__ ym, u16* __restrict__ prevp){
  int idx = blockIdx.x * blockDim.x + threadIdx.x;
  if (idx >= ROWS * 96) return;
  int r = idx / 96, c = idx - r * 96;
  int b = r / 800, t = r - b * 800;
  float v = 0.f;
  if (c < 80 && t > 0) v = ym[(u64)(b * 800 + (t - 1)) * 80 + c];
  prevp[idx] = f2bf(v);
}

__global__ void prep_w(const float* __restrict__ w1, const float* __restrict__ w2,
                       const float* __restrict__ wih, const float* __restrict__ pw,
                       const float* __restrict__ bih, const float* __restrict__ bhh,
                       const float* __restrict__ whh,
                       u16* __restrict__ w1p, u16* __restrict__ w2b,
                       u16* __restrict__ wihb, u16* __restrict__ projp,
                       float* __restrict__ bsum, u16* __restrict__ whhb){
  int idx = blockIdx.x * blockDim.x + threadIdx.x;
  const int n1 = 256 * 96, n2 = 256 * 256, n3 = 4096 * 768, n4 = 128 * 1536, n5 = 4096;
  const int n6 = 4096 * 1024;
  if (idx < n1){
    int r = idx / 96, c = idx - r * 96;
    w1p[idx] = (c < 80) ? f2bf(w1[r * 80 + c]) : (u16)0;
  } else if ((idx -= n1) < n2){
    w2b[idx] = f2bf(w2[idx]);
  } else if ((idx -= n2) < n3){
    wihb[idx] = f2bf(wih[idx]);
  } else if ((idx -= n3) < n4){
    int r = idx / 1536;
    projp[idx] = (r < 80) ? f2bf(pw[idx]) : (u16)0;
  } else if ((idx -= n4) < n5){
    bsum[idx] = bih[idx] + bhh[idx];
  } else if ((idx -= n5) < n6){
    whhb[idx] = f2bf(whh[idx]);
  }
}

// ------------------------------------------------------------ generic TN GEMM
// (standalone; used for prenet + projection)

template<int RELU, int OUTF32, int HASBIAS, int AMAP, int SPLIT>
__global__ __launch_bounds__(256, 2) void gemm_tn(
    const u16* __restrict__ A, const float* __restrict__ A2,
    const u16* __restrict__ W, void* __restrict__ Cv,
    const float* __restrict__ bias,
    int M, int K, int lda, int lda2, int ldw, int ldc, int nmax,
    int ksplit, int t0)
{
  __shared__ __align__(16) u16 As[128 * 32];
  __shared__ __align__(16) u16 Ws[128 * 32];
  const int tid = threadIdx.x;
  const int lane = tid & 63;
  const int wv = tid >> 6;
  const int wr = wv & 1, wc = wv >> 1;
  const int mtiles = M >> 7;
  const int ntiles = gridDim.x / mtiles;
  int bm, bn;
  if (mtiles & 7){
    bm = blockIdx.x % mtiles;
    bn = blockIdx.x / mtiles;
  } else {
    int per = 8 * ntiles;
    int g = blockIdx.x / per, rem = blockIdx.x % per;
    bm = g * 8 + (rem & 7);
    bn = rem >> 3;
  }
  const int m0 = bm << 7, n0 = bn << 7;
  const int KT = K >> 5;

  f32x4 acc[4][4] = {};

  const int r0 = tid >> 2, c0 = tid & 3;
  const int r1 = r0 + 64;
  const u16* Wb = W + (u64)n0 * ldw;
  const int ws0 = r0 * 32 + ((c0 ^ ((r0 >> 1) & 3)) << 3);
  const int ws1 = r1 * 32 + ((c0 ^ ((r1 >> 1) & 3)) << 3);

  auto rowmap = [&](int r) -> int {
    int gr = m0 + r;
    if (AMAP) return (gr & 31) * 800 + t0 + (gr >> 5);
    return gr;
  };
  const u64 ab0 = (u64)rowmap(r0) * lda;
  const u64 ab1 = (u64)rowmap(r1) * lda;
  const u64 af0 = SPLIT ? (u64)rowmap(r0) * lda2 : 0;
  const u64 af1 = SPLIT ? (u64)rowmap(r1) * lda2 : 0;

  auto aload = [&](u64 rb, u64 rf, int k) -> uint4 {
    if (SPLIT && k >= ksplit){
      const float* p = A2 + rf + (k - ksplit);
      const float4 a = *(const float4*)p;
      const float4 b = *(const float4*)(p + 4);
      uint4 r;
      r.x = (u32)f2bf(a.x) | ((u32)f2bf(a.y) << 16);
      r.y = (u32)f2bf(a.z) | ((u32)f2bf(a.w) << 16);
      r.z = (u32)f2bf(b.x) | ((u32)f2bf(b.y) << 16);
      r.w = (u32)f2bf(b.z) | ((u32)f2bf(b.w) << 16);
      return r;
    }
    return *(const uint4*)(A + rb + k);
  };

  uint4 ra0 = aload(ab0, af0, c0 * 8);
  uint4 ra1 = aload(ab1, af1, c0 * 8);
  uint4 rw0 = *(const uint4*)(Wb + r0 * ldw + c0 * 8);
  uint4 rw1 = *(const uint4*)(Wb + r1 * ldw + c0 * 8);

  const int r16 = lane & 15, cg = lane >> 4;

  for (int kt = 0; kt < KT; ++kt){
    *(uint4*)&As[ws0] = ra0;
    *(uint4*)&As[ws1] = ra1;
    *(uint4*)&Ws[ws0] = rw0;
    *(uint4*)&Ws[ws1] = rw1;
    __syncthreads();
    if (kt + 1 < KT){
      const int k0 = ((kt + 1) << 5) + c0 * 8;
      ra0 = aload(ab0, af0, k0);
      ra1 = aload(ab1, af1, k0);
      rw0 = *(const uint4*)(Wb + r0 * ldw + k0);
      rw1 = *(const uint4*)(Wb + r1 * ldw + k0);
    }
    short8 af[4], wf[4];
    #pragma unroll
    for (int mt = 0; mt < 4; ++mt){
      const int row = (wr << 6) + (mt << 4) + r16;
      af[mt] = *(const short8*)&As[(row << 5) + ((cg ^ ((row >> 1) & 3)) << 3)];
    }
    #pragma unroll
    for (int nt = 0; nt < 4; ++nt){
      const int row = (wc << 6) + (nt << 4) + r16;
      wf[nt] = *(const short8*)&Ws[(row << 5) + ((cg ^ ((row >> 1) & 3)) << 3)];
    }
    #pragma unroll
    for (int mt = 0; mt < 4; ++mt)
      #pragma unroll
      for (int nt = 0; nt < 4; ++nt)
        acc[mt][nt] = __builtin_amdgcn_mfma_f32_16x16x32_bf16(af[mt], wf[nt], acc[mt][nt], 0, 0, 0);
    __syncthreads();
  }

  #pragma unroll
  for (int nt = 0; nt < 4; ++nt){
    const int gn = n0 + (wc << 6) + (nt << 4) + r16;
    if (gn < nmax){
      float bv = 0.f;
      if (HASBIAS) bv = bias[gn];
      #pragma unroll
      for (int mt = 0; mt < 4; ++mt){
        #pragma unroll
        for (int r = 0; r < 4; ++r){
          const int gm = m0 + (wr << 6) + (mt << 4) + (cg << 2) + r;
          float v = acc[mt][nt][r] + bv;
          if (RELU) v = fmaxf(v, 0.f);
          if (OUTF32) ((float*)Cv)[(u64)gm * ldc + gn] = v;
          else        ((u16*)Cv)[(u64)gm * ldc + gn] = f2bf(v);
        }
      }
    }
  }
}

// ==================== fused persistent producer/consumer kernel ==============
// grid = 256 x 512 threads, 1 WG/CU (88KB LDS).
//   blockIdx 0..63   : LSTM workers.
//   blockIdx 64..255 : producers — gates GEMM chunk-by-chunk into 2-slot ring.
// r13 champion protocol (restored): h publish = packed-u32 relaxed AGENT
// atomics (MALL-serialized); h read = coalesced global_load_dwordx4 sc0+sc1
// (MALL-coherent, no fence, no invalidate); wave0-only flag poll + barrier
// broadcast (poll concurrency is first-order: r15's all-wave poll cost +22%);
// flag published by tid0 after B4's full-WG vmcnt drain.

__shared__ __align__(16) u16 fs_hsm[32 * 1024];  // 64KB worker h tile
__shared__ __align__(16) float fs_gsm[2048];     // 8KB worker gate exchange
__shared__ __align__(16) u16 fs_As[128 * 32];    // 8KB producer A tile
__shared__ __align__(16) u16 fs_Ws[128 * 32];    // 8KB producer W tile

__device__ void gemm_tile_512(
    const u16* __restrict__ pn, const float* __restrict__ memory,
    const u16* __restrict__ wihb, const float* __restrict__ bsum,
    u16* __restrict__ slot, int bm, int bn, int t0)
{
  const int tid = threadIdx.x;
  const bool act = (tid < 256);
  const int lane = tid & 63;
  const int wv4 = (tid >> 6) & 3;
  const int wr = wv4 & 1, wc = wv4 >> 1;
  const int m0 = bm << 7, n0 = bn << 7;
  const int KT = 24;   // K = 768

  f32x4 acc[4][4] = {};
  const int r0 = tid >> 2, c0 = tid & 3;
  const int r1 = r0 + 64;
  const u16* Wb = wihb + (u64)n0 * 768;
  const int ws0 = r0 * 32 + ((c0 ^ ((r0 >> 1) & 3)) << 3);
  const int ws1 = r1 * 32 + ((c0 ^ ((r1 >> 1) & 3)) << 3);

  auto rowmap = [&](int r) -> int {
    int gr = m0 + r;
    return (gr & 31) * 800 + t0 + (gr >> 5);
  };
  u64 ab0 = 0, ab1 = 0, af0 = 0, af1 = 0;
  if (act){
    ab0 = (u64)rowmap(r0) * 256;  af0 = (u64)rowmap(r0) * 512;
    ab1 = (u64)rowmap(r1) * 256;  af1 = (u64)rowmap(r1) * 512;
  }
  auto aload = [&](u64 rb, u64 rf, int k) -> uint4 {
    if (k >= 256){
      const float* p = memory + rf + (k - 256);
      const float4 a = *(const float4*)p;
      const float4 b = *(const float4*)(p + 4);
      uint4 r;
      r.x = (u32)f2bf(a.x) | ((u32)f2bf(a.y) << 16);
      r.y = (u32)f2bf(a.z) | ((u32)f2bf(a.w) << 16);
      r.z = (u32)f2bf(b.x) | ((u32)f2bf(b.y) << 16);
      r.w = (u32)f2bf(b.z) | ((u32)f2bf(b.w) << 16);
      return r;
    }
    return *(const uint4*)(pn + rb + k);
  };

  uint4 ra0, ra1, rw0, rw1;
  if (act){
    ra0 = aload(ab0, af0, c0 * 8);
    ra1 = aload(ab1, af1, c0 * 8);
    rw0 = *(const uint4*)(Wb + r0 * 768 + c0 * 8);
    rw1 = *(const uint4*)(Wb + r1 * 768 + c0 * 8);
  }
  const int r16 = lane & 15, cg = lane >> 4;

  for (int kt = 0; kt < KT; ++kt){
    if (act){
      *(uint4*)&fs_As[ws0] = ra0;
      *(uint4*)&fs_As[ws1] = ra1;
      *(uint4*)&fs_Ws[ws0] = rw0;
      *(uint4*)&fs_Ws[ws1] = rw1;
    }
    __syncthreads();
    if (act){
      if (kt + 1 < KT){
        const int k0 = ((kt + 1) << 5) + c0 * 8;
        ra0 = aload(ab0, af0, k0);
        ra1 = aload(ab1, af1, k0);
        rw0 = *(const uint4*)(Wb + r0 * 768 + k0);
        rw1 = *(const uint4*)(Wb + r1 * 768 + k0);
      }
      short8 af[4], wf[4];
      #pragma unroll
      for (int mt = 0; mt < 4; ++mt){
        const int row = (wr << 6) + (mt << 4) + r16;
        af[mt] = *(const short8*)&fs_As[(row << 5) + ((cg ^ ((row >> 1) & 3)) << 3)];
      }
      #pragma unroll
      for (int nt = 0; nt < 4; ++nt){
        const int row = (wc << 6) + (nt << 4) + r16;
        wf[nt] = *(const short8*)&fs_Ws[(row << 5) + ((cg ^ ((row >> 1) & 3)) << 3)];
      }
      #pragma unroll
      for (int mt = 0; mt < 4; ++mt)
        #pragma unroll
        for (int nt = 0; nt < 4; ++nt)
          acc[mt][nt] = __builtin_amdgcn_mfma_f32_16x16x32_bf16(af[mt], wf[nt], acc[mt][nt], 0, 0, 0);
    }
    __syncthreads();
  }

  if (act){
    #pragma unroll
    for (int nt = 0; nt < 4; ++nt){
      const int gn = n0 + (wc << 6) + (nt << 4) + r16;
      const float bv = bsum[gn];
      #pragma unroll
      for (int mt = 0; mt < 4; ++mt){
        #pragma unroll
        for (int r = 0; r < 4; ++r){
          const int gm = m0 + (wr << 6) + (mt << 4) + (cg << 2) + r;
          slot[(u64)gm * 4096 + gn] = f2bf(acc[mt][nt][r] + bv);
        }
      }
    }
  }
}

__global__ __launch_bounds__(512, 1) void fused(
    const u16* __restrict__ whhb, const u16* __restrict__ pn,
    const float* __restrict__ memory, const u16* __restrict__ wihb,
    const float* __restrict__ bsum, u16* __restrict__ ring,
    u16* __restrict__ hb, u16* __restrict__ hs,
    u32* wflags, u32* pflags, int CT, int nchunks)
{
  const int tid = threadIdx.x;
  const int lane = tid & 63;
  const int wv = tid >> 6;
  const u64 deadline = __builtin_amdgcn_s_memrealtime() + 100000000ull; // ~1s

  if (blockIdx.x >= 64){
    // ----------------------------------------------------------- producer
    const int p = blockIdx.x - 64;   // 0..191
    for (int c = 0; c < nchunks; ++c){
      const int t0 = c * CT;
      const int steps = (800 - t0 < CT) ? (800 - t0) : CT;
      if (c >= 2){
        if (wv == 0){
          const u32 need = (u32)((c - 1) * CT);
          u32 it = 0;
          while (1){
            u32 v = __hip_atomic_load(&wflags[lane << 5], __ATOMIC_RELAXED,
                                      __HIP_MEMORY_SCOPE_AGENT);
            if (__all((int)(v >= need))) break;
            __builtin_amdgcn_s_sleep(8);
            if (((++it) & 15u) == 0u &&
                __builtin_amdgcn_s_memrealtime() > deadline) break;
          }
        }
        __syncthreads();
      }
      const int mt = (steps * 32) >> 7;
      const int TPC = mt * 32;
      u16* slot = ring + (u64)(c & 1) * ((u64)CT << 17);
      for (int tau = p; tau < TPC; tau += 192){
        gemm_tile_512(pn, memory, wihb, bsum, slot, tau % mt, tau / mt, t0);
      }
      __syncthreads();   // all producer stores issued & vmcnt-drained
      if (wv == 0){
        __builtin_amdgcn_fence(__ATOMIC_RELEASE, "agent");  // wb L2 -> MALL
        if (tid == 0)
          __hip_atomic_store(&pflags[p << 5], (u32)(c + 1), __ATOMIC_RELAXED,
                             __HIP_MEMORY_SCOPE_AGENT);
      }
    }
    return;
  }

  // -------------------------------------------------------------- worker
  const int gate = wv & 3, mh = wv >> 2;
  const int u0 = blockIdx.x << 4;
  const int r16 = lane & 15, cg = lane >> 4;

  short8 wf[32];
  {
    const u16* wrow = whhb + (u64)((gate << 10) + u0 + r16) * 1024 + (cg << 3);
    #pragma unroll
    for (int kk = 0; kk < 32; ++kk)
      wf[kk] = *(const short8*)(wrow + (kk << 5));
    #pragma unroll
    for (int kk = 0; kk < 32; ++kk)
      asm volatile("" : "+v"(wf[kk]));
  }

  const int pb = tid >> 4, pu = tid & 15;
  float ccell = 0.f;
  const int arow = (mh << 4) + r16;
  const u16* abase = &fs_hsm[arow << 10];
  const int aswz = (arow & 7) << 3;

  int c = 0, i = 0;
  for (int t = 0; t < 800; ++t, ++i){
    if (i == CT){ c++; i = 0; }
    const bool boundary = (i == 0);
    const u16* gslot = ring + (u64)(c & 1) * ((u64)CT << 17);
    const u64 gb = ((u64)i * 32 + pb) * 4096 + u0 + pu;
    const int cur = t & 1;

    u16 gv0 = 0, gv1 = 0, gv2 = 0, gv3 = 0;
    if (!boundary){   // prefetch (chunk already gated at its first step)
      gv0 = gslot[gb];        gv1 = gslot[gb + 1024];
      gv2 = gslot[gb + 2048]; gv3 = gslot[gb + 3072];
    }
    if (boundary || t > 0){
      if (wv == 0){
        if (boundary){   // wait chunk c produced (192 flags, 3 per lane)
          const u32 need = (u32)(c + 1);
          u32 it = 0;
          while (1){
            u32 a = __hip_atomic_load(&pflags[lane << 5], __ATOMIC_RELAXED,
                                      __HIP_MEMORY_SCOPE_AGENT);
            u32 b = __hip_atomic_load(&pflags[(lane + 64) << 5], __ATOMIC_RELAXED,
                                      __HIP_MEMORY_SCOPE_AGENT);
            u32 d = __hip_atomic_load(&pflags[(lane + 128) << 5], __ATOMIC_RELAXED,
                                      __HIP_MEMORY_SCOPE_AGENT);
            u32 m = a < b ? a : b; m = m < d ? m : d;
            if (__all((int)(m >= need))) break;
            if (((++it) & 15u) == 0u &&
                __builtin_amdgcn_s_memrealtime() > deadline) break;
          }
        }
        if (t > 0){      // wait all WGs finished step t-1
          u32 it = 0;
          while (1){
            u32 v = __hip_atomic_load(&wflags[lane << 5], __ATOMIC_RELAXED,
                                      __HIP_MEMORY_SCOPE_AGENT);
            if (__all((int)(v >= (u32)t))) break;
            if (((++it) & 15u) == 0u &&
                __builtin_amdgcn_s_memrealtime() > deadline) break;
          }
        }
        if (boundary)    // only for ring-slot reuse (plain cached gslot loads)
          __builtin_amdgcn_fence(__ATOMIC_ACQUIRE, "agent");
      }
      __syncthreads();   // B1
    }
    if (boundary){
      gv0 = gslot[gb];        gv1 = gslot[gb + 1024];
      gv2 = gslot[gb + 2048]; gv3 = gslot[gb + 3072];
    }
    // stage h_t (64KB) into LDS via device-coherent coalesced reads:
    // global_load_dwordx4 with sc0+sc1 is serviced at the MALL (same
    // coherence point our h atomics write to) -> always fresh, no fence,
    // no L2 pollution.
    {
      const u16* hsrc = hb + cur * 32768;
      u32x4 hr[8];
      {
        u32x4 h0,h1,h2,h3,h4,h5,h6,h7;
        const u32 ob = (u32)tid << 4;
        asm volatile(
          "global_load_dwordx4 %0, %8, %16 sc0 sc1\n\t"
          "global_load_dwordx4 %1, %9, %16 sc0 sc1\n\t"
          "global_load_dwordx4 %2, %10, %16 sc0 sc1\n\t"
          "global_load_dwordx4 %3, %11, %16 sc0 sc1\n\t"
          "global_load_dwordx4 %4, %12, %16 sc0 sc1\n\t"
          "global_load_dwordx4 %5, %13, %16 sc0 sc1\n\t"
          "global_load_dwordx4 %6, %14, %16 sc0 sc1\n\t"
          "global_load_dwordx4 %7, %15, %16 sc0 sc1\n\t"
          "s_waitcnt vmcnt(0)"
          : "=&v"(h0), "=&v"(h1), "=&v"(h2), "=&v"(h3),
            "=&v"(h4), "=&v"(h5), "=&v"(h6), "=&v"(h7)
          : "v"(ob), "v"(ob + 8192u), "v"(ob + 16384u), "v"(ob + 24576u),
            "v"(ob + 32768u), "v"(ob + 40960u), "v"(ob + 49152u), "v"(ob + 57344u),
            "s"(hsrc)
          : "memory");
        __builtin_amdgcn_sched_barrier(0);
        hr[0]=h0; hr[1]=h1; hr[2]=h2; hr[3]=h3;
        hr[4]=h4; hr[5]=h5; hr[6]=h6; hr[7]=h7;
      }
      #pragma unroll
      for (int j = 0; j < 8; ++j){
        const int ci = (j << 9) + tid;
        const int row = ci >> 7, k16 = ci & 127;
        *(u32x4*)&fs_hsm[(row << 10) + ((k16 ^ (row & 7)) << 3)] = hr[j];
      }
    }
    __syncthreads();   // B2
    f32x4 acc = {};
    #pragma unroll
    for (int kk = 0; kk < 32; ++kk){
      const int k16 = (kk << 2) + cg;
      const short8 af = *(const short8*)&abase[((k16 << 3) ^ aswz)];
      acc = __builtin_amdgcn_mfma_f32_16x16x32_bf16(af, wf[kk], acc, 0, 0, 0);
    }
    #pragma unroll
    for (int r = 0; r < 4; ++r){
      const int m = (mh << 4) + (cg << 2) + r;
      fs_gsm[(gate << 9) + (m << 4) + r16] = acc[r];
    }
    __syncthreads();   // B3
    u16 hbits;
    {
      const int o = (pb << 4) + pu;
      const float gi = fs_gsm[o]        + bf2f(gv0);
      const float gf = fs_gsm[512 + o]  + bf2f(gv1);
      const float gg = fs_gsm[1024 + o] + bf2f(gv2);
      const float go = fs_gsm[1536 + o] + bf2f(gv3);
      ccell = sigf(gf) * ccell + sigf(gi) * tanh_(gg);
      const float h = sigf(go) * tanh_(ccell);
      hbits = f2bf(h);
      // publish h: packed pair -> relaxed agent atomic (MALL-serialized)
      const u32 other = (u32)(u16)__shfl_xor((int)(u32)hbits, 1);
      if ((tid & 1) == 0){
        const u32 w = ((u32)hbits) | (other << 16);
        u32* dst = (u32*)(void*)hb + ((cur ^ 1) * 16384 + (pb << 9) + (u0 >> 1) + (pu >> 1));
        __hip_atomic_store(dst, w, __ATOMIC_RELAXED, __HIP_MEMORY_SCOPE_AGENT);
      }
    }
    __syncthreads();   // B4: vmcnt drained -> h stores MALL-visible
    if (tid == 0)
      __hip_atomic_store(&wflags[blockIdx.x << 5], (u32)(t + 1), __ATOMIC_RELAXED,
                         __HIP_MEMORY_SCOPE_AGENT);
    // hs history store AFTER the flag (drains under the next step)
    hs[(((u64)pb * 800 + t) << 10) + u0 + pu] = hbits;
  }
}

// -------------------------------------------------------------------- launch

extern "C" void kernel_launch(void* const* d_in, const int* in_sizes, int n_in,
                              void* d_out, int out_size, void* d_ws, size_t ws_size,
                              hipStream_t stream){
  const float* memory = (const float*)d_in[0];
  const float* ymels  = (const float*)d_in[1];
  const float* w1     = (const float*)d_in[2];
  const float* w2     = (const float*)d_in[3];
  const float* wih    = (const float*)d_in[4];
  const float* whh    = (const float*)d_in[5];
  const float* bih    = (const float*)d_in[6];
  const float* bhh    = (const float*)d_in[7];
  const float* pw     = (const float*)d_in[8];
  const float* pbias  = (const float*)d_in[9];
  float* out = (float*)d_out;

  char* ws = (char*)d_ws;
  u64 off = 0;
  auto alloc = [&](u64 bytes) -> void* {
    void* p = ws + off;
    off += (bytes + 255) & ~255ull;
    return p;
  };
  u16* hs    = (u16*)alloc((u64)ROWS * 1024 * 2);   // 52.4 MB
  u16* pn    = (u16*)alloc((u64)ROWS * 256 * 2);    // 13.1 MB
  u16* wihb  = (u16*)alloc((u64)4096 * 768 * 2);    // 6.3 MB
  u16* whhb  = (u16*)alloc((u64)4096 * 1024 * 2);   // 8.4 MB
  u16* w1p   = (u16*)alloc(256 * 96 * 2);
  u16* w2b   = (u16*)alloc(256 * 256 * 2);
  u16* projp = (u16*)alloc(128 * 1536 * 2);
  float* bsum = (float*)alloc(4096 * 4);
  u16* hb    = (u16*)alloc(2 * 32768 * 2);
  u32* wflags = (u32*)alloc(64 * 32 * 4);
  u32* pflags = (u32*)alloc(192 * 32 * 4);
  u16* prevp = hs;                   // aliases (dead before hs written)
  u16* h1b   = hs + (8u << 20);

  int CT = 0;
  u16* ring = (u16*)(ws + off);
  if (ws_size > off){
    u64 avail = ws_size - off;
    CT = (int)(avail / (2ull * 32 * 4096 * 2));
    CT &= ~3;
    if (CT > 64) CT = 64;
  }
  if (CT < 8){
    float val = 1.0e6f + 10.0f * (float)(ws_size >> 20);
    sentinel_fill<<<256, 256, 0, stream>>>(out, out_size, val);
    return;
  }
  const int nchunks = (800 + CT - 1) / CT;

  initk<<<64, 256, 0, stream>>>(wflags, pflags, hb);
  prep_prev<<<(ROWS * 96) / 256, 256, 0, stream>>>(ymels, prevp);
  prep_w<<<(256*96 + 256*256 + 4096*768 + 128*1536 + 4096 + 4096*1024 + 255) / 256,
           256, 0, stream>>>(
      w1, w2, wih, pw, bih, bhh, whh, w1p, w2b, wihb, projp, bsum, whhb);

  // prenet layer 1: h1 = relu(prev @ w1^T)
  gemm_tn<1,0,0,0,0><<<200 * 2, 256, 0, stream>>>(prevp, nullptr, w1p, h1b, nullptr,
      ROWS, 96, 96, 0, 96, 256, 256, 0, 0);
  // prenet layer 2 -> pn (row stride 256)
  gemm_tn<1,0,0,0,0><<<200 * 2, 256, 0, stream>>>(h1b, nullptr, w2b, pn, nullptr,
      ROWS, 256, 256, 0, 256, 256, 256, 0, 0);

  // fused: producers (gates GEMM -> ring) + consumers (LSTM recurrence)
  fused<<<256, 512, 0, stream>>>(whhb, pn, memory, wihb, bsum, ring, hb, hs,
                                 wflags, pflags, CT, nchunks);

  // projection: mel = [hs|memory] @ proj_w^T + proj_b
  gemm_tn<0,1,1,0,1><<<200 * 1, 256, 0, stream>>>(hs, memory, projp, out, pbias,
      ROWS, 1536, 1024, 512, 1536, 80, 80, 1024, 0);
}